// Round 1
// baseline (460.745 us; speedup 1.0000x reference)
//
#include <hip/hip_runtime.h>
#include <math.h>

#define TB 128
#define TT 4096
#define TD 64

// ---- workspace layout (bytes) ----
#define XMEAN_OFF  0u
#define GRAM_OFF   2097152u
#define HIST_OFF   4194304u
#define COLSUM_OFF 6291456u
#define SCAL_OFF   6324224u
#define FIRST_OFF  6327808u
#define WS_TOTAL   6328320u

__device__ __forceinline__ float block_reduce_sum(float v, float* sbuf, int tid) {
#pragma unroll
  for (int o = 32; o; o >>= 1) v += __shfl_xor(v, o);
  __syncthreads();
  if ((tid & 63) == 0) sbuf[tid >> 6] = v;
  __syncthreads();
  return (sbuf[0] + sbuf[1]) + (sbuf[2] + sbuf[3]);
}

__device__ __forceinline__ int binof(float v) {
  int bi = (int)floorf(fmaf(v, 256.f, 2048.f));
  return bi < 0 ? 0 : (bi > 4095 ? 4095 : bi);
}

// ======================= kernel 1: x pass =======================
__global__ __launch_bounds__(256) void k1_xpass(const float* __restrict__ x,
    float* __restrict__ xmean, float* __restrict__ gram,
    unsigned* __restrict__ hist, float* __restrict__ colsum,
    float* __restrict__ scal) {
  __shared__ float rows[64 * 72];     // 64x64 tile, stride 72 (16B-aligned rows)
  __shared__ unsigned shist[4096];
  __shared__ float gred[4096];
  __shared__ float scol[64];
  __shared__ float sred[4];

  const int tid  = threadIdx.x;
  const int b    = blockIdx.y;
  const int s    = blockIdx.x;
  const int t0   = s << 10;           // 1024 rows per block
  const int lane = tid & 63;
  const int wv   = tid >> 6;
  const int TYr  = (lane >> 3) << 3;  // gram A base (0..56)
  const int TXr  = (lane & 7) << 3;   // gram B base
  const int lrow = tid >> 4;          // load row 0..15
  const int lcol = (tid & 15) << 2;   // load col (float idx)
  const int rr   = tid >> 2;          // rowsum row 0..63
  const int qq   = tid & 3;

  for (int i = tid; i < 4096; i += 256) shist[i] = 0u;
  if (tid < 64) scol[tid] = 0.f;

  float s1 = 0.f, s2 = 0.f, s3 = 0.f, s4 = 0.f, ac = 0.f;
  float cs[4] = {0.f, 0.f, 0.f, 0.f};
  float acc[8][8];
#pragma unroll
  for (int a = 0; a < 8; ++a)
#pragma unroll
    for (int c = 0; c < 8; ++c) acc[a][c] = 0.f;

  const float* xb = x + (size_t)b * (TT * TD);

  __syncthreads();

  for (int tile = 0; tile < 16; ++tile) {
    const int tbase = t0 + (tile << 6);
    // ---- load 64x64 tile: global -> LDS, with elementwise stats ----
#pragma unroll
    for (int k = 0; k < 4; ++k) {
      const int r = lrow + (k << 4);
      const float4 v = *(const float4*)(xb + (size_t)(tbase + r) * TD + lcol);
      const float x0 = v.x, x1 = v.y, x2 = v.z, x3 = v.w;
      const float q0 = x0 * x0, q1 = x1 * x1, q2 = x2 * x2, q3 = x3 * x3;
      s1 += (x0 + x1) + (x2 + x3);
      s2 += (q0 + q1) + (q2 + q3);
      s3 += (q0 * x0 + q1 * x1) + (q2 * x2 + q3 * x3);
      s4 += (q0 * q0 + q1 * q1) + (q2 * q2 + q3 * q3);
      cs[0] += x0; cs[1] += x1; cs[2] += x2; cs[3] += x3;
      atomicAdd(&shist[binof(x0)], 1u);
      atomicAdd(&shist[binof(x1)], 1u);
      atomicAdd(&shist[binof(x2)], 1u);
      atomicAdd(&shist[binof(x3)], 1u);
      *(float4*)(&rows[r * 72 + lcol]) = v;
    }
    __syncthreads();
    // ---- row sums (x_mean_t) + lag-1 autocorr ----
    {
      float4 c4[4];
      float rsum = 0.f;
#pragma unroll
      for (int j = 0; j < 4; ++j) {
        c4[j] = *(const float4*)(&rows[rr * 72 + (qq << 2) + (j << 4)]);
        rsum += (c4[j].x + c4[j].y) + (c4[j].z + c4[j].w);
      }
      float dot = 0.f;
      if (rr < 63) {
#pragma unroll
        for (int j = 0; j < 4; ++j) {
          const float4 n = *(const float4*)(&rows[(rr + 1) * 72 + (qq << 2) + (j << 4)]);
          dot += (c4[j].x * n.x + c4[j].y * n.y) + (c4[j].z * n.z + c4[j].w * n.w);
        }
      } else if (tbase + 64 < TT) {   // cross-tile boundary row from global
        const float* np = xb + (size_t)(tbase + 64) * TD;
#pragma unroll
        for (int j = 0; j < 4; ++j) {
          const float4 n = *(const float4*)(np + (qq << 2) + (j << 4));
          dot += (c4[j].x * n.x + c4[j].y * n.y) + (c4[j].z * n.z + c4[j].w * n.w);
        }
      }
      ac += dot;
      rsum += __shfl_xor(rsum, 1);
      rsum += __shfl_xor(rsum, 2);
      if (qq == 0) xmean[(size_t)b * TT + tbase + rr] = rsum * (1.f / 64.f);
    }
    // ---- raw gram: 8x8 register tile per lane, 4 wave-copies over t ----
    for (int tt = wv; tt < 64; tt += 4) {
      const float4* pa = (const float4*)(&rows[tt * 72 + TYr]);
      const float4 a0 = pa[0], a1 = pa[1];
      const float4* pb = (const float4*)(&rows[tt * 72 + TXr]);
      const float4 b0 = pb[0], b1 = pb[1];
      const float av[8] = {a0.x, a0.y, a0.z, a0.w, a1.x, a1.y, a1.z, a1.w};
      const float bv[8] = {b0.x, b0.y, b0.z, b0.w, b1.x, b1.y, b1.z, b1.w};
#pragma unroll
      for (int a = 0; a < 8; ++a)
#pragma unroll
        for (int c = 0; c < 8; ++c) acc[a][c] = fmaf(av[a], bv[c], acc[a][c]);
    }
    __syncthreads();
  }

  // ---- scalar reductions ----
  const float rac = block_reduce_sum(ac, sred, tid);
  const float r1 = block_reduce_sum(s1, sred, tid);
  const float r2 = block_reduce_sum(s2, sred, tid);
  const float r3 = block_reduce_sum(s3, sred, tid);
  const float r4 = block_reduce_sum(s4, sred, tid);
  if (tid == 0) {
    atomicAdd(&scal[0 * TB + b], rac);
    atomicAdd(&scal[1 * TB + b], r1);
    atomicAdd(&scal[2 * TB + b], r2);
    atomicAdd(&scal[3 * TB + b], r3);
    atomicAdd(&scal[4 * TB + b], r4);
  }
  // ---- column sums ----
#pragma unroll
  for (int c = 0; c < 4; ++c) atomicAdd(&scol[lcol + c], cs[c]);
  __syncthreads();
  if (tid < 64) atomicAdd(&colsum[b * 64 + tid], scol[tid]);
  // ---- gram: reduce 4 wave-copies in LDS, then global atomics ----
  for (int w = 0; w < 4; ++w) {
    if (wv == w) {
#pragma unroll
      for (int a = 0; a < 8; ++a)
#pragma unroll
        for (int c = 0; c < 8; ++c) {
          const int idx = (TYr + a) * 64 + TXr + c;
          if (w == 0) gred[idx] = acc[a][c];
          else gred[idx] += acc[a][c];
        }
    }
    __syncthreads();
  }
  float* gb = gram + (size_t)b * 4096;
  for (int i = tid; i < 4096; i += 256) atomicAdd(&gb[i], gred[i]);
  unsigned* hb = hist + (size_t)b * 4096;
  for (int i = tid; i < 4096; i += 256) {
    const unsigned hv = shist[i];
    if (hv) atomicAdd(&hb[i], hv);
  }
}

// ======================= kernel 2: mask pass =======================
__global__ __launch_bounds__(256) void k2_mask(const float* __restrict__ mk,
    float* __restrict__ scal, int* __restrict__ firstg) {
  __shared__ float sred[4];
  __shared__ int smax[4];
  const int tid = threadIdx.x;
  const int b = blockIdx.y;
  const int s = blockIdx.x;
  const int rr = tid >> 2, qq = tid & 3;
  const float* mb = mk + (size_t)b * (TT * TD);
  float osum = 0.f, o2 = 0.f;
  int fmax = 0;
  for (int it = 0; it < 16; ++it) {
    const int t = (s << 10) + (it << 6) + rr;
    const float* rp = mb + (size_t)t * TD;
    float a = 0.f;
#pragma unroll
    for (int j = 0; j < 4; ++j) {
      const float4 v = *(const float4*)(rp + (qq << 2) + (j << 4));
      a += (v.x + v.y) + (v.z + v.w);
    }
    a += __shfl_xor(a, 1);
    a += __shfl_xor(a, 2);
    if (qq == 0) {
      osum += a;
      o2 = fmaf(a, a, o2);
      if (a > 0.f) fmax = max(fmax, TT - t);
    }
  }
  const float ro = block_reduce_sum(osum, sred, tid);
  const float r2 = block_reduce_sum(o2, sred, tid);
#pragma unroll
  for (int o = 32; o; o >>= 1) fmax = max(fmax, __shfl_xor(fmax, o));
  if ((tid & 63) == 0) smax[tid >> 6] = fmax;
  __syncthreads();
  if (tid == 0) {
    atomicAdd(&scal[5 * TB + b], ro);
    atomicAdd(&scal[6 * TB + b], r2);
    atomicMax(&firstg[b], max(max(smax[0], smax[1]), max(smax[2], smax[3])));
  }
}

// ============== kernel 3: temporal + FFT spectral (1 block / batch) ==============
__global__ __launch_bounds__(256) void k3_spec(const float* __restrict__ xmean,
                                               float* __restrict__ out) {
  __shared__ float xm[4096];
  __shared__ float re[4096];
  __shared__ float im[4096];
  __shared__ float sred[4];
  __shared__ float smv[4];
  __shared__ int smi[4];
  const int tid = threadIdx.x;
  const int b = blockIdx.x;
  const float* xb = xmean + (size_t)b * TT;
  for (int i = tid; i < TT; i += 256) xm[i] = xb[i];
  __syncthreads();
  float ls = 0.f;
  for (int i = tid; i < TT; i += 256) ls += xm[i];
  const float meanv = block_reduce_sum(ls, sred, tid) * (1.f / TT);
  float tnum = 0.f, roc = 0.f;
  int pk = 0, zc = 0;
  for (int i = tid; i < TT; i += 256) {
    const float xi = xm[i];
    tnum += ((float)i - 2047.5f) * (xi - meanv);
    if (i < TT - 1) {
      const float d1 = xm[i + 1] - xi;
      roc += fabsf(d1);
      if (i >= 1) {
        const float d0 = xi - xm[i - 1];
        if (d1 * d0 < 0.f) ++pk;
      }
    }
    if (i >= 1) {
      if ((xi - meanv) * (xm[i - 1] - meanv) < 0.f) ++zc;
    }
  }
  tnum = block_reduce_sum(tnum, sred, tid);
  roc = block_reduce_sum(roc, sred, tid);
  const float pkf = block_reduce_sum((float)pk, sred, tid);
  const float zcf = block_reduce_sum((float)zc, sred, tid);
  if (tid == 0) {
    out[b * 17 + 1] = tnum / 5726622720.0f;      // sum(t_c^2), exact in fp32
    out[b * 17 + 9] = pkf * (1.f / 4094.f);
    out[b * 17 + 10] = zcf * (1.f / 4095.f);
    out[b * 17 + 11] = roc * (1.f / 4095.f);
  }
  // ---- radix-2 DIT FFT, bit-reversed input, in-place in LDS ----
  for (int i = tid; i < TT; i += 256) {
    re[i] = xm[__brev((unsigned)i) >> 20];
    im[i] = 0.f;
  }
  __syncthreads();
  int l2h = 0;
  for (int len = 2; len <= TT; len <<= 1, ++l2h) {
    const int half = len >> 1;
    const float ab = -6.283185307179586f / (float)len;
    for (int j = tid; j < TT / 2; j += 256) {
      const int pos = j & (half - 1);
      const int i0 = ((j >> l2h) << (l2h + 1)) + pos;
      const int i1 = i0 + half;
      float sn, cn;
      sincosf(ab * (float)pos, &sn, &cn);
      const float vr = re[i1], vi = im[i1];
      const float tr = cn * vr - sn * vi;
      const float ti = cn * vi + sn * vr;
      const float ur = re[i0], ui = im[i0];
      re[i0] = ur + tr; im[i0] = ui + ti;
      re[i1] = ur - tr; im[i1] = ui - ti;
    }
    __syncthreads();
  }
  // ---- power spectrum bins 0..2048: sum, argmax, entropy ----
  float ps = 0.f, bmax = -1.f;
  int bidx = 0;
  for (int k = tid; k <= 2048; k += 256) {
    const float p = re[k] * re[k] + im[k] * im[k];
    ps += p;
    if (p > bmax) { bmax = p; bidx = k; }
  }
  ps = block_reduce_sum(ps, sred, tid);
#pragma unroll
  for (int o = 32; o; o >>= 1) {
    const float ov = __shfl_xor(bmax, o);
    const int oi = __shfl_xor(bidx, o);
    if (ov > bmax || (ov == bmax && oi < bidx)) { bmax = ov; bidx = oi; }
  }
  if ((tid & 63) == 0) { smv[tid >> 6] = bmax; smi[tid >> 6] = bidx; }
  __syncthreads();
  float ent = 0.f;
  const float inv = 1.f / (ps + 1e-8f);
  for (int k = tid; k <= 2048; k += 256) {
    const float p = (re[k] * re[k] + im[k] * im[k]) * inv;
    ent -= p * logf(p + 1e-8f);
  }
  ent = block_reduce_sum(ent, sred, tid);
  if (tid == 0) {
    float bv = smv[0]; int bi = smi[0];
    for (int w = 1; w < 4; ++w)
      if (smv[w] > bv || (smv[w] == bv && smi[w] < bi)) { bv = smv[w]; bi = smi[w]; }
    out[b * 17 + 2] = (float)bi * (1.f / 2048.f);
    out[b * 17 + 3] = ent;
  }
}

// ============== kernel 4: gram features + quantiles + assembly ==============
__global__ __launch_bounds__(256) void k4_final(const float* __restrict__ gram,
    const float* __restrict__ colsum, const unsigned* __restrict__ hist,
    const float* __restrict__ scal, const int* __restrict__ firstg,
    float* __restrict__ out) {
  __shared__ float Lg[64 * 65];      // centered gram, pad-65 -> conflict-free rows
  __shared__ float cs[64];
  __shared__ float sd[64];
  __shared__ unsigned h[4096];
  __shared__ unsigned chs[256];
  __shared__ float sred[4];
  const int tid = threadIdx.x;
  const int b = blockIdx.x;
  if (tid < 64) cs[tid] = colsum[b * 64 + tid];
  for (int i = tid; i < 4096; i += 256) h[i] = hist[(size_t)b * 4096 + i];
  __syncthreads();
  const float* gb = gram + (size_t)b * 4096;
  for (int i = tid; i < 4096; i += 256) {
    const int d = i >> 6, e = i & 63;
    Lg[d * 65 + e] = gb[i] - cs[d] * cs[e] * (1.f / 4096.f);
  }
  {
    unsigned c = 0;
#pragma unroll
    for (int j = 0; j < 16; ++j) c += h[tid * 16 + j];
    chs[tid] = c;
  }
  __syncthreads();
  if (tid < 64) sd[tid] = sqrtf(Lg[tid * 65 + tid] * (1.f / 4095.f));
  __syncthreads();
  float mcs = 0.f, trc = 0.f;
  for (int i = tid; i < 4096; i += 256) {
    const int d = i >> 6, e = i & 63;
    const float g = Lg[d * 65 + e];
    if (d != e) mcs += (g * (1.f / 4095.f)) / (sd[d] * sd[e] + 1e-8f);
    else trc += g;
  }
  mcs = block_reduce_sum(mcs, sred, tid);
  trc = block_reduce_sum(trc, sred, tid);
  // ---- power iteration on wave 0 (v in registers, shfl broadcast) ----
  float lam = 0.f;
  if (tid < 64) {
    const float* rowp = &Lg[tid * 65];
    float v = 1.f + 0.001f * (float)tid;
    float n2 = 1.f;
    for (int it = 0; it < 48; ++it) {
      float w0 = 0.f, w1 = 0.f, w2 = 0.f, w3 = 0.f;
#pragma unroll
      for (int e = 0; e < 64; e += 4) {
        w0 = fmaf(rowp[e],     __shfl(v, e),     w0);
        w1 = fmaf(rowp[e + 1], __shfl(v, e + 1), w1);
        w2 = fmaf(rowp[e + 2], __shfl(v, e + 2), w2);
        w3 = fmaf(rowp[e + 3], __shfl(v, e + 3), w3);
      }
      const float w = (w0 + w1) + (w2 + w3);
      n2 = w * w;
#pragma unroll
      for (int o = 32; o; o >>= 1) n2 += __shfl_xor(n2, o);
      v = w * rsqrtf(n2);
    }
    lam = sqrtf(n2);
  }
  __syncthreads();
  if (tid == 0) {
    // quantiles via histogram interpolation (jnp 'linear' between order stats)
    const unsigned ranks[6] = {65535u, 65536u, 131071u, 131072u, 196607u, 196608u};
    float osv[6];
    for (int qi = 0; qi < 6; ++qi) {
      const unsigned r = ranks[qi];
      unsigned cum = 0; int c = 0;
      while (c < 255 && cum + chs[c] <= r) { cum += chs[c]; ++c; }
      int bin = c << 4;
      while (bin < 4095 && cum + h[bin] <= r) { cum += h[bin]; ++bin; }
      const float cnt = (float)max(h[bin], 1u);
      osv[qi] = ((float)bin * (1.f / 256.f) - 8.f) +
                (((float)(r - cum) + 0.5f) / cnt) * (1.f / 256.f);
    }
    const float q25 = 0.25f * osv[0] + 0.75f * osv[1];
    const float q50 = 0.5f * (osv[2] + osv[3]);
    const float q75 = 0.75f * osv[4] + 0.25f * osv[5];
    const float N = 262144.f;
    const float m1 = scal[1 * TB + b] / N;
    const float M2 = scal[2 * TB + b] / N;
    const float M3 = scal[3 * TB + b] / N;
    const float M4 = scal[4 * TB + b] / N;
    const float mu2 = M2 - m1 * m1;
    const float mu3 = M3 - 3.f * m1 * M2 + 2.f * m1 * m1 * m1;
    const float mu4 = M4 - 4.f * m1 * M3 + 6.f * m1 * m1 * M2 - 3.f * m1 * m1 * m1 * m1;
    const float skew = mu3 / (sqrtf(mu2) * mu2 + 1e-8f);
    const float kurt = mu4 / (mu2 * mu2 + 1e-8f);
    const float ac = scal[0 * TB + b] * (1.f / 262080.f);
    const float msum = scal[5 * TB + b];
    const float o2s = scal[6 * TB + b];
    const float missing = 1.f - msum / 262144.f;
    const float sdm = msum * (1.f / 64.f) * (1.f / 4096.f);
    const float dvar = (o2s * (1.f / 4096.f) - 4096.f * sdm * sdm) * (1.f / 4095.f);
    const int fm = firstg[b];
    const float fobs = fm > 0 ? (float)(4096 - fm) * (1.f / 4096.f) : 0.f;
    float* ob = out + b * 17;
    ob[0] = ac;
    ob[4] = skew; ob[5] = kurt;
    ob[6] = q25; ob[7] = q50; ob[8] = q75;
    ob[12] = missing; ob[13] = dvar; ob[14] = fobs;
    ob[15] = mcs / (4032.f + 1e-8f);
    ob[16] = lam / trc;
  }
}

extern "C" void kernel_launch(void* const* d_in, const int* in_sizes, int n_in,
                              void* d_out, int out_size, void* d_ws, size_t ws_size,
                              hipStream_t stream) {
  (void)in_sizes; (void)n_in; (void)out_size; (void)ws_size;
  const float* x = (const float*)d_in[0];
  const float* mask = (const float*)d_in[1];
  float* out = (float*)d_out;
  char* ws = (char*)d_ws;
  float* xmean = (float*)(ws + XMEAN_OFF);
  float* gram = (float*)(ws + GRAM_OFF);
  unsigned* hist = (unsigned*)(ws + HIST_OFF);
  float* colsum = (float*)(ws + COLSUM_OFF);
  float* scal = (float*)(ws + SCAL_OFF);
  int* firstg = (int*)(ws + FIRST_OFF);

  hipMemsetAsync(d_ws, 0, WS_TOTAL, stream);

  dim3 g1(4, TB);
  k1_xpass<<<g1, 256, 0, stream>>>(x, xmean, gram, hist, colsum, scal);
  k2_mask<<<g1, 256, 0, stream>>>(mask, scal, firstg);
  k3_spec<<<TB, 256, 0, stream>>>(xmean, out);
  k4_final<<<TB, 256, 0, stream>>>(gram, colsum, hist, scal, firstg, out);
}

// Round 2
// 360.073 us; speedup vs baseline: 1.2796x; 1.2796x over previous
//
#include <hip/hip_runtime.h>
#include <math.h>

#define TB 128
#define TT 4096
#define TD 64

// ---- workspace layout (bytes): zeroed prefix first, xmean (no zero) last ----
#define GRAM_OFF   0u
#define HIST_OFF   2097152u
#define COLSUM_OFF 4194304u
#define SCAL_OFF   4227072u
#define FIRST_OFF  4230656u
#define ZERO_BYTES 4231168u
#define XMEAN_OFF  4231168u

typedef float  f32x4  __attribute__((ext_vector_type(4)));
typedef short  s16x8  __attribute__((ext_vector_type(8)));

__device__ __forceinline__ float brs4(float v, float* sbuf, int tid) {
#pragma unroll
  for (int o = 32; o; o >>= 1) v += __shfl_xor(v, o);
  __syncthreads();
  if ((tid & 63) == 0) sbuf[tid >> 6] = v;
  __syncthreads();
  return (sbuf[0] + sbuf[1]) + (sbuf[2] + sbuf[3]);
}

__device__ __forceinline__ float brs8(float v, float* sbuf, int tid) {
#pragma unroll
  for (int o = 32; o; o >>= 1) v += __shfl_xor(v, o);
  __syncthreads();
  if ((tid & 63) == 0) sbuf[tid >> 6] = v;
  __syncthreads();
  return ((sbuf[0] + sbuf[1]) + (sbuf[2] + sbuf[3])) +
         ((sbuf[4] + sbuf[5]) + (sbuf[6] + sbuf[7]));
}

__device__ __forceinline__ int binof(float v) {
  int bi = (int)floorf(fmaf(v, 256.f, 2048.f));
  return bi < 0 ? 0 : (bi > 4095 ? 4095 : bi);
}

__device__ __forceinline__ unsigned short f2bf(float f) {  // RNE f32->bf16
  unsigned u = __float_as_uint(f);
  return (unsigned short)((u + 0x7FFFu + ((u >> 16) & 1u)) >> 16);
}

// ============ kernel 1: fused x+mask pass (stats, hist, xmean, MFMA gram) ============
__global__ __launch_bounds__(256) void k1_fused(const float* __restrict__ x,
    const float* __restrict__ mk, float* __restrict__ xmean,
    float* __restrict__ gram, unsigned* __restrict__ hist,
    float* __restrict__ colsum, float* __restrict__ scal,
    int* __restrict__ firstg) {
  __shared__ __align__(16) float rows[64 * 72];        // fp32 tile, t-major
  __shared__ __align__(16) unsigned short Xt[64 * 72]; // bf16 tile, d-major (Xt[d][t])
  __shared__ unsigned shist[4096];
  __shared__ float scol[64];
  __shared__ float sred[4];
  __shared__ int smax[4];

  const int tid  = threadIdx.x;
  const int b    = blockIdx.y;
  const int s    = blockIdx.x;
  const int t0   = s << 10;            // 1024 timesteps per block
  const int lane = tid & 63;
  const int wv   = tid >> 6;
  const int r0   = (tid >> 4) << 2;    // 4 consecutive rows per thread
  const int lcol = (tid & 15) << 2;
  const int rr   = tid >> 2;           // rowsum mapping
  const int qq   = tid & 3;
  // MFMA: wave wv owns 32x32 quadrant (mb0, nb0), split into 4 16x16 blocks
  const int mb0 = (wv & 1) << 5;
  const int nb0 = (wv >> 1) << 5;
  const int ml  = lane & 15;
  const int qk  = (lane >> 4) << 3;    // k-offset within 32-chunk

  for (int i = tid; i < 4096; i += 256) shist[i] = 0u;
  if (tid < 64) scol[tid] = 0.f;

  float s1 = 0.f, s2 = 0.f, s3 = 0.f, s4 = 0.f, ac = 0.f;
  float osum = 0.f, o2 = 0.f;
  int fmax = 0;
  float cs[4] = {0.f, 0.f, 0.f, 0.f};
  f32x4 acc[2][2];
#pragma unroll
  for (int mi = 0; mi < 2; ++mi)
#pragma unroll
    for (int ni = 0; ni < 2; ++ni) acc[mi][ni] = (f32x4)0.f;

  const float* xb = x + (size_t)b * (TT * TD);
  const float* mb = mk + (size_t)b * (TT * TD);

  __syncthreads();

  for (int tile = 0; tile < 16; ++tile) {
    const int tbase = t0 + (tile << 6);
    float4 v[4];
    // ---- x load (4 consecutive rows) + elementwise stats + fp32 LDS ----
#pragma unroll
    for (int k = 0; k < 4; ++k) {
      const int r = r0 + k;
      v[k] = *(const float4*)(xb + (size_t)(tbase + r) * TD + lcol);
      const float x0 = v[k].x, x1 = v[k].y, x2 = v[k].z, x3 = v[k].w;
      const float q0 = x0 * x0, q1 = x1 * x1, q2 = x2 * x2, q3 = x3 * x3;
      s1 += (x0 + x1) + (x2 + x3);
      s2 += (q0 + q1) + (q2 + q3);
      s3 += (q0 * x0 + q1 * x1) + (q2 * x2 + q3 * x3);
      s4 += (q0 * q0 + q1 * q1) + (q2 * q2 + q3 * q3);
      cs[0] += x0; cs[1] += x1; cs[2] += x2; cs[3] += x3;
      atomicAdd(&shist[binof(x0)], 1u);
      atomicAdd(&shist[binof(x1)], 1u);
      atomicAdd(&shist[binof(x2)], 1u);
      atomicAdd(&shist[binof(x3)], 1u);
      *(float4*)(&rows[r * 72 + lcol]) = v[k];
    }
    // ---- bf16 transposed tile: Xt[d][t], 4x4 block -> 4 x b64 writes ----
#pragma unroll
    for (int j = 0; j < 4; ++j) {
      const float e0 = j == 0 ? v[0].x : (j == 1 ? v[0].y : (j == 2 ? v[0].z : v[0].w));
      const float e1 = j == 0 ? v[1].x : (j == 1 ? v[1].y : (j == 2 ? v[1].z : v[1].w));
      const float e2 = j == 0 ? v[2].x : (j == 1 ? v[2].y : (j == 2 ? v[2].z : v[2].w));
      const float e3 = j == 0 ? v[3].x : (j == 1 ? v[3].y : (j == 2 ? v[3].z : v[3].w));
      uint2 pw;
      pw.x = (unsigned)f2bf(e0) | ((unsigned)f2bf(e1) << 16);
      pw.y = (unsigned)f2bf(e2) | ((unsigned)f2bf(e3) << 16);
      *(uint2*)(&Xt[(lcol + j) * 72 + r0]) = pw;
    }
    // ---- mask: per-row obs counts ----
#pragma unroll
    for (int k = 0; k < 4; ++k) {
      const int t = tbase + r0 + k;
      const float4 mv = *(const float4*)(mb + (size_t)t * TD + lcol);
      float ms = (mv.x + mv.y) + (mv.z + mv.w);
      ms += __shfl_xor(ms, 1);
      ms += __shfl_xor(ms, 2);
      ms += __shfl_xor(ms, 4);
      ms += __shfl_xor(ms, 8);
      if ((tid & 15) == 0) {
        osum += ms;
        o2 = fmaf(ms, ms, o2);
        if (ms > 0.f) fmax = max(fmax, TT - t);
      }
    }
    __syncthreads();
    // ---- row sums (x_mean_t) + lag-1 autocorr from fp32 tile ----
    {
      float4 c4[4];
      float rsum = 0.f;
#pragma unroll
      for (int j = 0; j < 4; ++j) {
        c4[j] = *(const float4*)(&rows[rr * 72 + (qq << 2) + (j << 4)]);
        rsum += (c4[j].x + c4[j].y) + (c4[j].z + c4[j].w);
      }
      float dot = 0.f;
      if (rr < 63) {
#pragma unroll
        for (int j = 0; j < 4; ++j) {
          const float4 n = *(const float4*)(&rows[(rr + 1) * 72 + (qq << 2) + (j << 4)]);
          dot += (c4[j].x * n.x + c4[j].y * n.y) + (c4[j].z * n.z + c4[j].w * n.w);
        }
      } else if (tbase + 64 < TT) {
        const float* np = xb + (size_t)(tbase + 64) * TD;
#pragma unroll
        for (int j = 0; j < 4; ++j) {
          const float4 n = *(const float4*)(np + (qq << 2) + (j << 4));
          dot += (c4[j].x * n.x + c4[j].y * n.y) + (c4[j].z * n.z + c4[j].w * n.w);
        }
      }
      ac += dot;
      rsum += __shfl_xor(rsum, 1);
      rsum += __shfl_xor(rsum, 2);
      if (qq == 0) xmean[(size_t)b * TT + tbase + rr] = rsum * (1.f / 64.f);
    }
    // ---- MFMA gram: 2x2 16x16 blocks per wave, K=64 in two 32-chunks ----
#pragma unroll
    for (int kk = 0; kk < 2; ++kk) {
      const int ko = (kk << 5) + qk;
      s16x8 af[2], bf[2];
#pragma unroll
      for (int mi = 0; mi < 2; ++mi)
        af[mi] = *(const s16x8*)(&Xt[(mb0 + (mi << 4) + ml) * 72 + ko]);
#pragma unroll
      for (int ni = 0; ni < 2; ++ni)
        bf[ni] = *(const s16x8*)(&Xt[(nb0 + (ni << 4) + ml) * 72 + ko]);
#pragma unroll
      for (int mi = 0; mi < 2; ++mi)
#pragma unroll
        for (int ni = 0; ni < 2; ++ni)
          acc[mi][ni] = __builtin_amdgcn_mfma_f32_16x16x32_bf16(
              af[mi], bf[ni], acc[mi][ni], 0, 0, 0);
    }
    __syncthreads();
  }

  // ---- scalar reductions ----
  const float rac = brs4(ac, sred, tid);
  const float r1 = brs4(s1, sred, tid);
  const float r2 = brs4(s2, sred, tid);
  const float r3 = brs4(s3, sred, tid);
  const float r4 = brs4(s4, sred, tid);
  const float ro = brs4(osum, sred, tid);
  const float ro2 = brs4(o2, sred, tid);
#pragma unroll
  for (int o = 32; o; o >>= 1) fmax = max(fmax, __shfl_xor(fmax, o));
  if ((tid & 63) == 0) smax[tid >> 6] = fmax;
  __syncthreads();
  if (tid == 0) {
    atomicAdd(&scal[0 * TB + b], rac);
    atomicAdd(&scal[1 * TB + b], r1);
    atomicAdd(&scal[2 * TB + b], r2);
    atomicAdd(&scal[3 * TB + b], r3);
    atomicAdd(&scal[4 * TB + b], r4);
    atomicAdd(&scal[5 * TB + b], ro);
    atomicAdd(&scal[6 * TB + b], ro2);
    atomicMax(&firstg[b], max(max(smax[0], smax[1]), max(smax[2], smax[3])));
  }
  // ---- column sums ----
#pragma unroll
  for (int c = 0; c < 4; ++c) atomicAdd(&scol[lcol + c], cs[c]);
  __syncthreads();
  if (tid < 64) atomicAdd(&colsum[b * 64 + tid], scol[tid]);
  // ---- gram accumulate: C/D layout col=lane&15, row=(lane>>4)*4+reg ----
  float* gb = gram + (size_t)b * 4096;
  {
    const int crow = (lane >> 4) << 2;
    const int ccol = lane & 15;
#pragma unroll
    for (int mi = 0; mi < 2; ++mi)
#pragma unroll
      for (int ni = 0; ni < 2; ++ni) {
        const int gr0 = mb0 + (mi << 4) + crow;
        const int gc = nb0 + (ni << 4) + ccol;
#pragma unroll
        for (int rg = 0; rg < 4; ++rg)
          atomicAdd(&gb[(gr0 + rg) * 64 + gc], acc[mi][ni][rg]);
      }
  }
  // ---- histogram flush ----
  unsigned* hb = hist + (size_t)b * 4096;
  for (int i = tid; i < 4096; i += 256) {
    const unsigned hv = shist[i];
    if (hv) atomicAdd(&hb[i], hv);
  }
}

// ============ kernel 34: block-specialized spectral (0..127) + final (128..255) ============
__global__ __launch_bounds__(512) void k34(const float* __restrict__ xmean,
    const float* __restrict__ gram, const float* __restrict__ colsum,
    const unsigned* __restrict__ hist, const float* __restrict__ scal,
    const int* __restrict__ firstg, float* __restrict__ out) {
  __shared__ __align__(16) char arena[49152];
  __shared__ float sred[8];
  __shared__ float smv[8];
  __shared__ int smi[8];
  __shared__ float cssh[64];
  __shared__ float sdsh[64];
  __shared__ float osv_s[6];
  const int tid = threadIdx.x;

  if (blockIdx.x < 128) {
    // ================= spectral path =================
    const int b = blockIdx.x;
    float* xm = (float*)arena;
    float* re = xm + 4096;
    float* im = re + 4096;
    const float* xb = xmean + (size_t)b * TT;
    for (int i = tid; i < TT; i += 512) xm[i] = xb[i];
    __syncthreads();
    float ls = 0.f;
    for (int i = tid; i < TT; i += 512) ls += xm[i];
    const float meanv = brs8(ls, sred, tid) * (1.f / TT);
    float tnum = 0.f, roc = 0.f;
    int pk = 0, zc = 0;
    for (int i = tid; i < TT; i += 512) {
      const float xi = xm[i];
      tnum += ((float)i - 2047.5f) * (xi - meanv);
      if (i < TT - 1) {
        const float d1 = xm[i + 1] - xi;
        roc += fabsf(d1);
        if (i >= 1) {
          const float d0 = xi - xm[i - 1];
          if (d1 * d0 < 0.f) ++pk;
        }
      }
      if (i >= 1) {
        if ((xi - meanv) * (xm[i - 1] - meanv) < 0.f) ++zc;
      }
    }
    tnum = brs8(tnum, sred, tid);
    roc = brs8(roc, sred, tid);
    const float pkf = brs8((float)pk, sred, tid);
    const float zcf = brs8((float)zc, sred, tid);
    if (tid == 0) {
      out[b * 17 + 1] = tnum / 5726622720.0f;
      out[b * 17 + 9] = pkf * (1.f / 4094.f);
      out[b * 17 + 10] = zcf * (1.f / 4095.f);
      out[b * 17 + 11] = roc * (1.f / 4095.f);
    }
    // radix-2 DIT FFT in LDS
    for (int i = tid; i < TT; i += 512) {
      re[i] = xm[__brev((unsigned)i) >> 20];
      im[i] = 0.f;
    }
    __syncthreads();
    int l2h = 0;
    for (int len = 2; len <= TT; len <<= 1, ++l2h) {
      const int half = len >> 1;
      const float ab = -6.283185307179586f / (float)len;
      for (int j = tid; j < TT / 2; j += 512) {
        const int pos = j & (half - 1);
        const int i0 = ((j >> l2h) << (l2h + 1)) + pos;
        const int i1 = i0 + half;
        float sn, cn;
        __sincosf(ab * (float)pos, &sn, &cn);
        const float vr = re[i1], vi = im[i1];
        const float tr = cn * vr - sn * vi;
        const float ti = cn * vi + sn * vr;
        const float ur = re[i0], ui = im[i0];
        re[i0] = ur + tr; im[i0] = ui + ti;
        re[i1] = ur - tr; im[i1] = ui - ti;
      }
      __syncthreads();
    }
    // power spectrum: sum, argmax, entropy over bins 0..2048
    float ps = 0.f, bmaxv = -1.f;
    int bidx = 0;
    for (int k = tid; k <= 2048; k += 512) {
      const float p = re[k] * re[k] + im[k] * im[k];
      ps += p;
      if (p > bmaxv) { bmaxv = p; bidx = k; }
    }
    ps = brs8(ps, sred, tid);
#pragma unroll
    for (int o = 32; o; o >>= 1) {
      const float ov = __shfl_xor(bmaxv, o);
      const int oi = __shfl_xor(bidx, o);
      if (ov > bmaxv || (ov == bmaxv && oi < bidx)) { bmaxv = ov; bidx = oi; }
    }
    if ((tid & 63) == 0) { smv[tid >> 6] = bmaxv; smi[tid >> 6] = bidx; }
    __syncthreads();
    float ent = 0.f;
    const float inv = 1.f / (ps + 1e-8f);
    for (int k = tid; k <= 2048; k += 512) {
      const float p = (re[k] * re[k] + im[k] * im[k]) * inv;
      ent -= p * __logf(p + 1e-8f);
    }
    ent = brs8(ent, sred, tid);
    if (tid == 0) {
      float bv = smv[0]; int bi = smi[0];
      for (int w = 1; w < 8; ++w)
        if (smv[w] > bv || (smv[w] == bv && smi[w] < bi)) { bv = smv[w]; bi = smi[w]; }
      out[b * 17 + 2] = (float)bi * (1.f / 2048.f);
      out[b * 17 + 3] = ent;
    }
  } else {
    // ================= final path =================
    const int b = blockIdx.x - 128;
    float* Lg = (float*)arena;                          // 64 x 65
    unsigned* h = (unsigned*)(arena + 16640);           // 4096
    unsigned* cumc = (unsigned*)(arena + 16640 + 16384);// 256
    if (tid < 64) cssh[tid] = colsum[b * 64 + tid];
    for (int i = tid; i < 4096; i += 512) h[i] = hist[(size_t)b * 4096 + i];
    __syncthreads();
    const float* gb = gram + (size_t)b * 4096;
    for (int i = tid; i < 4096; i += 512) {
      const int d = i >> 6, e = i & 63;
      Lg[d * 65 + e] = gb[i] - cssh[d] * cssh[e] * (1.f / 4096.f);
    }
    unsigned chs_own = 0;
    if (tid < 256) {
#pragma unroll
      for (int j = 0; j < 16; ++j) chs_own += h[(tid << 4) + j];
      cumc[tid] = chs_own;
    }
    __syncthreads();
    if (tid < 64) sdsh[tid] = sqrtf(Lg[tid * 65 + tid] * (1.f / 4095.f));
    // inclusive scan over 256 coarse bins
    for (int off = 1; off < 256; off <<= 1) {
      unsigned add = 0;
      if (tid < 256 && tid >= off) add = cumc[tid - off];
      __syncthreads();
      if (tid < 256) cumc[tid] += add;
      __syncthreads();
    }
    float mcs = 0.f, trc = 0.f;
    for (int i = tid; i < 4096; i += 512) {
      const int d = i >> 6, e = i & 63;
      const float g = Lg[d * 65 + e];
      if (d != e) mcs += (g * (1.f / 4095.f)) / (sdsh[d] * sdsh[e] + 1e-8f);
      else trc += g;
    }
    mcs = brs8(mcs, sred, tid);
    trc = brs8(trc, sred, tid);
    // parallel quantile refinement
    if (tid < 256) {
      const unsigned ranks[6] = {65535u, 65536u, 131071u, 131072u, 196607u, 196608u};
      const unsigned incl = cumc[tid];
      const unsigned excl = incl - chs_own;
#pragma unroll
      for (int qi = 0; qi < 6; ++qi) {
        const unsigned r = ranks[qi];
        if (excl <= r && r < incl) {
          int bin = tid << 4;
          unsigned cum = excl;
          while (bin < 4095 && cum + h[bin] <= r) { cum += h[bin]; ++bin; }
          const float cnt = (float)max(h[bin], 1u);
          osv_s[qi] = ((float)bin * (1.f / 256.f) - 8.f) +
                      (((float)(r - cum) + 0.5f) / cnt) * (1.f / 256.f);
        }
      }
    }
    // power iteration on wave 0
    float lam = 0.f;
    if (tid < 64) {
      const float* rowp = &Lg[tid * 65];
      float v = 1.f + 0.001f * (float)tid;
      float n2 = 1.f;
      for (int it = 0; it < 48; ++it) {
        float w0 = 0.f, w1 = 0.f, w2 = 0.f, w3 = 0.f;
#pragma unroll
        for (int e = 0; e < 64; e += 4) {
          w0 = fmaf(rowp[e],     __shfl(v, e),     w0);
          w1 = fmaf(rowp[e + 1], __shfl(v, e + 1), w1);
          w2 = fmaf(rowp[e + 2], __shfl(v, e + 2), w2);
          w3 = fmaf(rowp[e + 3], __shfl(v, e + 3), w3);
        }
        const float w = (w0 + w1) + (w2 + w3);
        n2 = w * w;
#pragma unroll
        for (int o = 32; o; o >>= 1) n2 += __shfl_xor(n2, o);
        v = w * rsqrtf(n2);
      }
      lam = sqrtf(n2);
    }
    __syncthreads();
    if (tid == 0) {
      const float q25 = 0.25f * osv_s[0] + 0.75f * osv_s[1];
      const float q50 = 0.5f * (osv_s[2] + osv_s[3]);
      const float q75 = 0.75f * osv_s[4] + 0.25f * osv_s[5];
      const float N = 262144.f;
      const float m1 = scal[1 * TB + b] / N;
      const float M2 = scal[2 * TB + b] / N;
      const float M3 = scal[3 * TB + b] / N;
      const float M4 = scal[4 * TB + b] / N;
      const float mu2 = M2 - m1 * m1;
      const float mu3 = M3 - 3.f * m1 * M2 + 2.f * m1 * m1 * m1;
      const float mu4 = M4 - 4.f * m1 * M3 + 6.f * m1 * m1 * M2 - 3.f * m1 * m1 * m1 * m1;
      const float skew = mu3 / (sqrtf(mu2) * mu2 + 1e-8f);
      const float kurt = mu4 / (mu2 * mu2 + 1e-8f);
      const float acv = scal[0 * TB + b] * (1.f / 262080.f);
      const float msum = scal[5 * TB + b];
      const float o2s = scal[6 * TB + b];
      const float missing = 1.f - msum / 262144.f;
      const float sdm = msum * (1.f / 64.f) * (1.f / 4096.f);
      const float dvar = (o2s * (1.f / 4096.f) - 4096.f * sdm * sdm) * (1.f / 4095.f);
      const int fm = firstg[b];
      const float fobs = fm > 0 ? (float)(4096 - fm) * (1.f / 4096.f) : 0.f;
      float* ob = out + b * 17;
      ob[0] = acv;
      ob[4] = skew; ob[5] = kurt;
      ob[6] = q25; ob[7] = q50; ob[8] = q75;
      ob[12] = missing; ob[13] = dvar; ob[14] = fobs;
      ob[15] = mcs / (4032.f + 1e-8f);
      ob[16] = lam / trc;
    }
  }
}

extern "C" void kernel_launch(void* const* d_in, const int* in_sizes, int n_in,
                              void* d_out, int out_size, void* d_ws, size_t ws_size,
                              hipStream_t stream) {
  (void)in_sizes; (void)n_in; (void)out_size; (void)ws_size;
  const float* x = (const float*)d_in[0];
  const float* mask = (const float*)d_in[1];
  float* out = (float*)d_out;
  char* ws = (char*)d_ws;
  float* gram = (float*)(ws + GRAM_OFF);
  unsigned* hist = (unsigned*)(ws + HIST_OFF);
  float* colsum = (float*)(ws + COLSUM_OFF);
  float* scal = (float*)(ws + SCAL_OFF);
  int* firstg = (int*)(ws + FIRST_OFF);
  float* xmean = (float*)(ws + XMEAN_OFF);

  hipMemsetAsync(d_ws, 0, ZERO_BYTES, stream);

  dim3 g1(4, TB);
  k1_fused<<<g1, 256, 0, stream>>>(x, mask, xmean, gram, hist, colsum, scal, firstg);
  k34<<<256, 512, 0, stream>>>(xmean, gram, colsum, hist, scal, firstg, out);
}